// Round 1
// baseline (176.582 us; speedup 1.0000x reference)
//
#include <hip/hip_runtime.h>

#define NEG_BIG (-3.0e38f)

// One block = 256 threads = 4 waves; each wave handles 2 samples (32 lanes each).
// Lane m (within its 32-lane half) owns correlation lags sh = 8m .. 8m+7.
__global__ __launch_bounds__(256) void avsync_kernel(
    const float* __restrict__ video, const float* __restrict__ audio,
    const float* __restrict__ W1, const float* __restrict__ b1,
    const float* __restrict__ W2, const float* __restrict__ b2,
    float* __restrict__ out) {
  // per wave, per half: apad[384] (zero-padded audio) | v[128]
  __shared__ float lds[4][2][512];

  const int tid  = threadIdx.x;
  const int wid  = tid >> 6;
  const int lane = tid & 63;
  const int half = lane >> 5;
  const int m    = lane & 31;
  const int b    = (int)blockIdx.x * 8 + wid * 2 + half;

  float* ap = &lds[wid][half][0];
  float* vl = &lds[wid][half][384];

  const float4 vr = *reinterpret_cast<const float4*>(video + (size_t)b * 128 + 4 * m);
  const float4 ar = *reinterpret_cast<const float4*>(audio + (size_t)b * 128 + 4 * m);

  // row norms
  float pv = vr.x * vr.x + vr.y * vr.y + vr.z * vr.z + vr.w * vr.w;
  float pa = ar.x * ar.x + ar.y * ar.y + ar.z * ar.z + ar.w * ar.w;
#pragma unroll
  for (int off = 1; off < 32; off <<= 1) {
    pv += __shfl_xor(pv, off, 32);
    pa += __shfl_xor(pa, off, 32);
  }
  const float nv = sqrtf(pv);
  const float na = sqrtf(pa);
  const float iv = 1.0f / fmaxf(nv, 1e-12f);
  const float ia = 1.0f / fmaxf(na, 1e-12f);

  float4 v4, a4;
  v4.x = vr.x * iv; v4.y = vr.y * iv; v4.z = vr.z * iv; v4.w = vr.w * iv;
  a4.x = ar.x * ia; a4.y = ar.y * ia; a4.z = ar.z * ia; a4.w = ar.w * ia;

  // stage: zeros at apad[0..127] and apad[256..383], a at apad[128..255], v at vl
  float4 z4; z4.x = z4.y = z4.z = z4.w = 0.0f;
  reinterpret_cast<float4*>(ap)[m]      = z4;
  reinterpret_cast<float4*>(ap)[64 + m] = z4;
  reinterpret_cast<float4*>(ap)[32 + m] = a4;
  reinterpret_cast<float4*>(vl)[m]      = v4;

  // phase statistic on normalized difference (values are small, fast intrinsics fine)
  float sc = __cosf(v4.x - a4.x) + __cosf(v4.y - a4.y) + __cosf(v4.z - a4.z) + __cosf(v4.w - a4.w);
  float ss = __sinf(v4.x - a4.x) + __sinf(v4.y - a4.y) + __sinf(v4.z - a4.z) + __sinf(v4.w - a4.w);
#pragma unroll
  for (int off = 1; off < 32; off <<= 1) {
    sc += __shfl_xor(sc, off, 32);
    ss += __shfl_xor(ss, off, 32);
  }

  __syncthreads();

  // correlation: corr[sh] = sum_j v[j] * apad[255 + j - sh], sh = 8m + q
  // sliding 12-wide window W[k] <-> apad[248 + 4c - 8m + k]
  float acc[8] = {0.f, 0.f, 0.f, 0.f, 0.f, 0.f, 0.f, 0.f};
  float W[12];
  {
    const float* wp = ap + (248 - 8 * m);
    const float4 t0 = *reinterpret_cast<const float4*>(wp);
    const float4 t1 = *reinterpret_cast<const float4*>(wp + 4);
    W[0] = t0.x; W[1] = t0.y; W[2] = t0.z; W[3] = t0.w;
    W[4] = t1.x; W[5] = t1.y; W[6] = t1.z; W[7] = t1.w;
  }
  const float* rp = ap + (256 - 8 * m);
#pragma unroll
  for (int c = 0; c < 32; ++c) {
    const float4 tn = *reinterpret_cast<const float4*>(rp + 4 * c);
    W[8] = tn.x; W[9] = tn.y; W[10] = tn.z; W[11] = tn.w;
    const float4 vv = *reinterpret_cast<const float4*>(vl + 4 * c);
#pragma unroll
    for (int q = 0; q < 8; ++q) acc[q] = fmaf(vv.x, W[7 - q], acc[q]);
#pragma unroll
    for (int q = 0; q < 8; ++q) acc[q] = fmaf(vv.y, W[8 - q], acc[q]);
#pragma unroll
    for (int q = 0; q < 8; ++q) acc[q] = fmaf(vv.z, W[9 - q], acc[q]);
#pragma unroll
    for (int q = 0; q < 8; ++q) acc[q] = fmaf(vv.w, W[10 - q], acc[q]);
#pragma unroll
    for (int k = 0; k < 8; ++k) W[k] = W[k + 4];
  }

  // per-lane stats over its 8 lags (ascending order -> first-occurrence argmax)
  float sum = 0.f, ssq = 0.f, mx = NEG_BIG;
  int mi = 0;
#pragma unroll
  for (int q = 0; q < 8; ++q) {
    const int sh = 8 * m + q;
    const bool realLag = (sh < 255);
    const float cv = acc[q];
    const float cs = realLag ? cv : 0.f;
    sum += cs;
    ssq += cs * cs;
    const float cm = realLag ? cv : NEG_BIG;
    if (cm > mx) { mx = cm; mi = sh; }
  }
  // cross-lane reduce over the 32-lane half (max with min-index tie-break)
#pragma unroll
  for (int off = 1; off < 32; off <<= 1) {
    const float ov = __shfl_xor(mx, off, 32);
    const int   oi = __shfl_xor(mi, off, 32);
    if (ov > mx || (ov == mx && oi < mi)) { mx = ov; mi = oi; }
    sum += __shfl_xor(sum, off, 32);
    ssq += __shfl_xor(ssq, off, 32);
  }

  const float delay = (float)mi - 127.0f;
  const float rv = nv / fmaxf(nv, 1e-12f);   // ||v_normalized||
  const float ra = na / fmaxf(na, 1e-12f);
  const float cstr = mx / (rv * ra + 1e-6f);
  const float mean = sum * (1.0f / 255.0f);
  const float var  = fmaxf(ssq * (1.0f / 255.0f) - mean * mean, 0.0f);
  const float cstd = sqrtf(var);
  const float ve = rv * rv, ae = ra * ra;
  const float er = ve / (ae + 1e-6f);
  const float mc = sc * (1.0f / 128.0f), ms = ss * (1.0f / 128.0f);
  const float pc = sqrtf(mc * mc + ms * ms);
  const float cons = 1.0f / (1.0f + fabsf(delay));

  const float s0 = delay * 0.1f;
  const float s1 = cstr;
  const float s2 = cstd;
  const float s3 = er;
  const float s4 = pc;
  const float s5 = cons;

  // MLP: each lane computes output feature f = m for its sample
  float h[16];
#pragma unroll
  for (int k = 0; k < 16; ++k) {
    float acch = b1[k];
    acch = fmaf(s0, W1[0 * 16 + k], acch);
    acch = fmaf(s1, W1[1 * 16 + k], acch);
    acch = fmaf(s2, W1[2 * 16 + k], acch);
    acch = fmaf(s3, W1[3 * 16 + k], acch);
    acch = fmaf(s4, W1[4 * 16 + k], acch);
    acch = fmaf(s5, W1[5 * 16 + k], acch);
    h[k] = fmaxf(acch, 0.0f);
  }
  float o = b2[m];
#pragma unroll
  for (int k = 0; k < 16; ++k) o = fmaf(h[k], W2[k * 32 + m], o);
  out[(size_t)b * 32 + m] = o;
}

extern "C" void kernel_launch(void* const* d_in, const int* in_sizes, int n_in,
                              void* d_out, int out_size, void* d_ws, size_t ws_size,
                              hipStream_t stream) {
  const float* video = (const float*)d_in[0];
  const float* audio = (const float*)d_in[1];
  const float* W1 = (const float*)d_in[2];
  const float* b1 = (const float*)d_in[3];
  const float* W2 = (const float*)d_in[4];
  const float* b2 = (const float*)d_in[5];
  float* out = (float*)d_out;

  const int B = in_sizes[0] / 128;        // 65536 samples
  const int blocks = B / 8;               // 2 samples/wave * 4 waves/block
  avsync_kernel<<<blocks, 256, 0, stream>>>(video, audio, W1, b1, W2, b2, out);
}